// Round 6
// baseline (233.953 us; speedup 1.0000x reference)
//
#include <hip/hip_runtime.h>

typedef float f32x4 __attribute__((ext_vector_type(4)));

#define DIM 512
#define WPB 4                 // waves per block
#define BLOCK 256
#define GRID 1024             // 4096 waves, 8 row-pairs per wave

// DPP cross-lane (VALU pipe): xor1, xor2, half-mirror, row-mirror; + one
// ds_swizzle xor16 (BitMode stays in the 32-group) = 32-lane allreduce.
template <int CTRL>
__device__ __forceinline__ float dpp_mov(float x) {
    return __int_as_float(
        __builtin_amdgcn_update_dpp(0, __float_as_int(x), CTRL, 0xF, 0xF, true));
}
__device__ __forceinline__ float red32_add(float x) {
    x += dpp_mov<0xB1>(x);
    x += dpp_mov<0x4E>(x);
    x += dpp_mov<0x141>(x);
    x += dpp_mov<0x140>(x);
    x += __int_as_float(__builtin_amdgcn_ds_swizzle(__float_as_int(x), (16 << 10) | 0x1f));
    return x;
}
__device__ __forceinline__ float red32_max(float x) {
    x = fmaxf(x, dpp_mov<0xB1>(x));
    x = fmaxf(x, dpp_mov<0x4E>(x));
    x = fmaxf(x, dpp_mov<0x141>(x));
    x = fmaxf(x, dpp_mov<0x140>(x));
    x = fmaxf(x, __int_as_float(__builtin_amdgcn_ds_swizzle(__float_as_int(x), (16 << 10) | 0x1f)));
    return x;
}

// Async global->LDS, 16B per lane. LDS dest is WAVE-UNIFORM base; HW scatters
// lane i to base + i*16. Zero VGPRs held -> compiler cannot sink the prefetch.
__device__ __forceinline__ void load_lds16(const f32x4* g, f32x4* l) {
    __builtin_amdgcn_global_load_lds(
        (const __attribute__((address_space(1))) void*)g,
        (__attribute__((address_space(3))) void*)l, 16, 0, 0);
}

// gfx9 s_waitcnt immediates: vmcnt[3:0]=imm[3:0], vmcnt[5:4]=imm[15:14],
// expcnt=imm[6:4], lgkmcnt=imm[11:8].
#define WAIT_VM0   0x0F70   // vmcnt(0) only
#define WAIT_VM4   0x0F74   // vmcnt(4) only
#define WAIT_LGKM0 0xC07F   // lgkmcnt(0) only

// Persistent: 2 rows per wave (lanes 0-31 / 32-63), 8 pairs per wave.
// Pipeline per iteration: ds_read staged pair -> refill buffer for pair+1
// (loads fly across the whole compute) -> Michelot -> NT stores -> vmcnt(4)
// (staging loads retired; the 4 newer stores may remain in flight).
__global__ __launch_bounds__(BLOCK) void sparsemax_kernel(
    const float* __restrict__ x, float* __restrict__ out, int batch) {
    __shared__ f32x4 lbuf[WPB][256];   // 4 KB per wave
    const int wv   = threadIdx.x >> 6;
    const int lane = threadIdx.x & 63;
    const int half = lane >> 5;
    const int l    = lane & 31;
    const int nw   = GRID * WPB;
    const int npair = batch >> 1;

    f32x4* buf = lbuf[wv];
    int p = blockIdx.x * WPB + wv;
    if (p >= npair) return;

    const f32x4* xp = reinterpret_cast<const f32x4*>(x);
    f32x4*       op = reinterpret_cast<f32x4*>(out);
    const int    po = half * 128 + l;     // lane's f32x4 offset within a pair

    // prologue: stage first pair, full drain (only once)
    {
        const f32x4* g = xp + (size_t)p * 256 + po;
#pragma unroll
        for (int j = 0; j < 4; ++j) load_lds16(g + j * 32, buf + j * 64);
    }
    __builtin_amdgcn_s_waitcnt(WAIT_VM0);

    while (true) {
        // consume staged pair
        f32x4 c0 = buf[lane], c1 = buf[64 + lane], c2 = buf[128 + lane], c3 = buf[192 + lane];
        __builtin_amdgcn_s_waitcnt(WAIT_LGKM0);   // reads done -> buf reusable

        // refill for next pair; in flight during all of the compute below
        const int  pn   = p + nw;
        const bool more = pn < npair;             // wave-uniform
        if (more) {
            const f32x4* g = xp + (size_t)pn * 256 + po;
#pragma unroll
            for (int j = 0; j < 4; ++j) load_lds16(g + j * 32, buf + j * 64);
        }

        float z[16] = {c0.x, c0.y, c0.z, c0.w, c1.x, c1.y, c1.z, c1.w,
                       c2.x, c2.y, c2.z, c2.w, c3.x, c3.y, c3.z, c3.w};

        // tau0 = rowmax - 1 (valid lower bound: p_max <= 1)
        float m = z[0];
#pragma unroll
        for (int j = 1; j < 16; ++j) m = fmaxf(m, z[j]);
        m = red32_max(m);
        float tau = m - 1.0f;

        // Michelot: tau' = (S-1)/K over {z > tau}; exact finite convergence
        // (support sets nested & shrinking; K stable <=> fixed point).
        int kp0 = -1, kp1 = -1;
        for (int it = 0; it < 32; ++it) {
            float S = 0.f;
            int K0 = 0, K1 = 0;
#pragma unroll
            for (int j = 0; j < 16; ++j) {
                const bool in = z[j] > tau;
                const unsigned long long b = __ballot(in);
                K0 += __popc((unsigned)b);
                K1 += __popc((unsigned)(b >> 32));
                S += in ? z[j] : 0.f;
            }
            S = red32_add(S);
            if (K0 == kp0 && K1 == kp1) break;
            kp0 = K0; kp1 = K1;
            const float K = (float)(half ? K1 : K0);
            tau = (S - 1.0f) * __builtin_amdgcn_rcpf(K);   // K >= 1
        }

        // epilogue: NT stores (write-once; keeps input L3-resident)
        f32x4 o[4];
#pragma unroll
        for (int j = 0; j < 16; ++j) o[j >> 2][j & 3] = fmaxf(0.f, z[j] - tau);
        f32x4* q = op + (size_t)p * 256 + po;
        __builtin_nontemporal_store(o[0], q);
        __builtin_nontemporal_store(o[1], q + 32);
        __builtin_nontemporal_store(o[2], q + 64);
        __builtin_nontemporal_store(o[3], q + 96);

        if (!more) break;
        // 4 oldest (staging loads) retired; 4 newest (stores) may stay in flight
        __builtin_amdgcn_s_waitcnt(WAIT_VM4);
        p = pn;
    }
}

extern "C" void kernel_launch(void* const* d_in, const int* in_sizes, int n_in,
                              void* d_out, int out_size, void* d_ws, size_t ws_size,
                              hipStream_t stream) {
    const float* x = (const float*)d_in[0];
    float* out     = (float*)d_out;
    const int batch = in_sizes[0] / DIM;  // 65536
    sparsemax_kernel<<<GRID, BLOCK, 0, stream>>>(x, out, batch);
}